// Round 14
// baseline (623.826 us; speedup 1.0000x reference)
//
#include <hip/hip_runtime.h>
#include <math.h>

typedef unsigned short u16;
typedef unsigned int u32;
typedef __bf16 bf16x8 __attribute__((ext_vector_type(8)));
typedef float floatx4 __attribute__((ext_vector_type(4)));

#define MFMA16(a, b, c) __builtin_amdgcn_mfma_f32_16x16x32_bf16((a), (b), (c), 0, 0, 0)

__device__ __forceinline__ float bf2f(u16 u) {
  u32 x = ((u32)u) << 16; float f; __builtin_memcpy(&f, &x, 4); return f;
}
__device__ __forceinline__ u16 f2bf(float f) {
  u32 x; __builtin_memcpy(&x, &f, 4);
  return (u16)((x + 0x7FFFu + ((x >> 16) & 1u)) >> 16);  // RNE
}
__device__ __forceinline__ void store_dual(u16* outp, float v) {
  u32 h = (u32)f2bf(v);
  *(u32*)outp = (h << 16) | h;
}
__device__ __forceinline__ bf16x8 ld8(const u16* p) { return *(const bf16x8*)p; }

__device__ __forceinline__ void gload16(const void* g, void* l) {
  __builtin_amdgcn_global_load_lds((const __attribute__((address_space(1))) u32*)g,
                                   (__attribute__((address_space(3))) u32*)l, 16, 0, 0);
}

__device__ __forceinline__ float wred64(float v) {
#pragma unroll
  for (int off = 32; off > 0; off >>= 1) v += __shfl_down(v, off, 64);
  return v;
}

__device__ __forceinline__ void store_final(u16* outp, float ev, int flag) {
  if (!(ev == ev) || fabsf(ev) > 1e37f) ev = -12345.0f - 1000.0f * (float)flag;
  if (flag) *(float*)outp = ev;
  else outp[0] = f2bf(ev);
}

// ---------------- diagnostics ----------------
__global__ void k_sentinel(u16* outp, float v) {
  if (threadIdx.x == 0 && blockIdx.x == 0) store_dual(outp, v);
}

// ---------------- input dtype detect: flag=1 if f32, 0 if bf16 ----------------
__global__ void k_detect(const u32* __restrict__ raw, int* __restrict__ flag) {
  if (threadIdx.x == 0 && blockIdx.x == 0) {
    int outliers = 0;
    for (int i = 0; i < 64; ++i) {
      u32 lo = raw[i] & 0xFFFFu;
      int e = (int)((lo >> 7) & 0xFF);
      if (e < 100 || e > 150) ++outliers;
    }
    *flag = (outliers > 16) ? 1 : 0;
  }
}

// ---------------- fused dtype-aware convert (24 jobs, one launch) ----------------
struct CvtJobs {
  const void* src[24];
  u16* dst[24];
  int n[24];
  int bstart[25];
};
__global__ __launch_bounds__(256) void k_cvt_all(CvtJobs a, const int* __restrict__ flag) {
  const int b = blockIdx.x, tid = threadIdx.x;
  int j = 0;
  while (b >= a.bstart[j + 1]) ++j;
  const int base = (b - a.bstart[j]) * 4096;
  const int n = a.n[j];
  if (*flag) {
    const float* s = (const float*)a.src[j];
    u16* d = a.dst[j];
    for (int i0 = base + tid * 4; i0 < base + 4096 && i0 < n; i0 += 1024) {
      float4 v = *(const float4*)(s + i0);
      u16 o[4] = {f2bf(v.x), f2bf(v.y), f2bf(v.z), f2bf(v.w)};
      __builtin_memcpy(d + i0, o, 8);
    }
  } else {
    const u16* s = (const u16*)a.src[j];
    u16* d = a.dst[j];
    for (int i0 = base + tid * 4; i0 < base + 4096 && i0 < n; i0 += 1024)
      *(uint2*)(d + i0) = *(const uint2*)(s + i0);
  }
}

// ---------------- fused transpose (5 jobs) ----------------
struct TrJobs {
  const u16* src[5];
  u16* dst[5];
  int R[5], C[5];
  int bstart[6];
};
__global__ __launch_bounds__(256) void k_transpose_all(TrJobs a) {
  const int b = blockIdx.x, tid = threadIdx.x;
  int j = 0;
  while (b >= a.bstart[j + 1]) ++j;
  const int base = (b - a.bstart[j]) * 1024;
  const int R = a.R[j], C = a.C[j], tot = R * C;
  const u16* in = a.src[j];
  u16* out = a.dst[j];
#pragma unroll
  for (int k = 0; k < 4; ++k) {
    int i = base + tid + k * 256;
    if (i < tot) { int r = i / C, c = i - r * C; out[c * R + r] = in[i]; }
  }
}

// ---------------- fused per-row 1/||x|| (3 jobs) ----------------
struct RnJobs {
  const u16* X[3];
  float* out[3];
  int rows[3];
  int bstart[4];
};
__global__ __launch_bounds__(256) void k_rownorm_all(RnJobs a) {
  const int b = blockIdx.x;
  int j = 0;
  while (b >= a.bstart[j + 1]) ++j;
  const int w = threadIdx.x >> 6, lane = threadIdx.x & 63;
  const int row = (b - a.bstart[j]) * 4 + w;
  if (row >= a.rows[j]) return;
  const u16* p = a.X[j] + (size_t)row * 256 + lane * 4;
  float s = 0.f;
#pragma unroll
  for (int i = 0; i < 4; ++i) { float v = bf2f(p[i]); s += v * v; }
  s = wred64(s);
  if (lane == 0) a.out[j][row] = rsqrtf(s);
}

// ---------------- start-vector MLP (1 block) -> ex0[128] ----------------
__global__ __launch_bounds__(256) void k_start(
    const u16* __restrict__ se,
    const u16* __restrict__ sw0, const u16* __restrict__ sb0,
    const u16* __restrict__ sw1, const u16* __restrict__ sb1,
    const u16* __restrict__ sw2, const u16* __restrict__ sb2,
    const u16* __restrict__ sw3, const u16* __restrict__ sb3,
    const u16* __restrict__ sw4, const u16* __restrict__ sb4,
    const u16* __restrict__ proj, float* __restrict__ ex0) {
  __shared__ float xa[256], xb[256], xc[256], red[256];
  const int tid = threadIdx.x;
  xa[tid] = bf2f(se[tid]);
  __syncthreads();
  float acc = bf2f(sb0[tid]);
  for (int k = 0; k < 256; ++k) acc += xa[k] * bf2f(sw0[k * 256 + tid]);
  xb[tid] = acc;
  __syncthreads();
  acc = bf2f(sb1[tid]);
  for (int k = 0; k < 256; ++k) acc += xb[k] * bf2f(sw1[k * 256 + tid]);
  xc[tid] = fmaxf(acc, 0.f);
  __syncthreads();
  acc = bf2f(sb2[tid]);
  for (int k = 0; k < 256; ++k) acc += xc[k] * bf2f(sw2[k * 256 + tid]);
  xa[tid] = fmaxf(acc, 0.f) + xb[tid];
  __syncthreads();
  acc = bf2f(sb3[tid]);
  for (int k = 0; k < 256; ++k) acc += xa[k] * bf2f(sw3[k * 256 + tid]);
  xc[tid] = fmaxf(acc, 0.f);
  __syncthreads();
  acc = bf2f(sb4[tid]);
  for (int k = 0; k < 256; ++k) acc += xc[k] * bf2f(sw4[k * 256 + tid]);
  xb[tid] = fmaxf(acc, 0.f) + xa[tid];
  __syncthreads();
  red[tid] = xb[tid] * xb[tid];
  __syncthreads();
  for (int s = 128; s > 0; s >>= 1) {
    if (tid < s) red[tid] += red[tid + s];
    __syncthreads();
  }
  const float rs = rsqrtf(red[0]);
  xa[tid] = xb[tid] * rs;
  __syncthreads();
  if (tid < 128) {
    float a = 0.f;
    for (int k = 0; k < 256; ++k) a += xa[k] * bf2f(proj[k * 128 + tid]);
    ex0[tid] = expf(a);
  }
}

// ---------------- preterminal MLP + fused rs_ft ----------------
__global__ __launch_bounds__(256) void k_mlp(
    const u16* __restrict__ X0,
    const u16* __restrict__ w1T, const u16* __restrict__ b1,
    const u16* __restrict__ w2T, const u16* __restrict__ b2,
    const u16* __restrict__ w3T, const u16* __restrict__ b3,
    const u16* __restrict__ w4T, const u16* __restrict__ b4,
    u16* __restrict__ FT, float* __restrict__ rs_ft) {
  __shared__ __align__(16) u16 Y[2][64][264];
  const int tid = threadIdx.x, lane = tid & 63, w = tid >> 6;
  const int m16 = lane & 15, kg = lane >> 4;
  const int rbl = w * 16;
  const int rbg = blockIdx.x * 64 + rbl;
  const floatx4 z4 = {0.f, 0.f, 0.f, 0.f};
  floatx4 acc[16];

#pragma unroll
  for (int ct = 0; ct < 16; ++ct) acc[ct] = z4;
  for (int k0 = 0; k0 < 256; k0 += 32) {
    bf16x8 a = ld8(X0 + (size_t)(rbg + m16) * 256 + k0 + kg * 8);
#pragma unroll
    for (int ct = 0; ct < 16; ++ct)
      acc[ct] = MFMA16(a, ld8(w1T + (ct * 16 + m16) * 256 + k0 + kg * 8), acc[ct]);
  }
#pragma unroll
  for (int ct = 0; ct < 16; ++ct) {
    const int col = ct * 16 + m16;
    const float bv = bf2f(b1[col]);
#pragma unroll
    for (int r = 0; r < 4; ++r)
      Y[0][rbl + kg * 4 + r][col] = f2bf(fmaxf(acc[ct][r] + bv, 0.f));
  }
  __syncthreads();
#pragma unroll
  for (int ct = 0; ct < 16; ++ct) acc[ct] = z4;
  for (int k0 = 0; k0 < 256; k0 += 32) {
    bf16x8 a = *(const bf16x8*)(&Y[0][rbl + m16][k0 + kg * 8]);
#pragma unroll
    for (int ct = 0; ct < 16; ++ct)
      acc[ct] = MFMA16(a, ld8(w2T + (ct * 16 + m16) * 256 + k0 + kg * 8), acc[ct]);
  }
#pragma unroll
  for (int ct = 0; ct < 16; ++ct) {
    const int col = ct * 16 + m16;
    const float bv = bf2f(b2[col]);
#pragma unroll
    for (int r = 0; r < 4; ++r) {
      const int gr = rbg + kg * 4 + r;
      float v = fmaxf(acc[ct][r] + bv, 0.f) + bf2f(X0[(size_t)gr * 256 + col]);
      Y[1][rbl + kg * 4 + r][col] = f2bf(v);
    }
  }
  __syncthreads();
#pragma unroll
  for (int ct = 0; ct < 16; ++ct) acc[ct] = z4;
  for (int k0 = 0; k0 < 256; k0 += 32) {
    bf16x8 a = *(const bf16x8*)(&Y[1][rbl + m16][k0 + kg * 8]);
#pragma unroll
    for (int ct = 0; ct < 16; ++ct)
      acc[ct] = MFMA16(a, ld8(w3T + (ct * 16 + m16) * 256 + k0 + kg * 8), acc[ct]);
  }
#pragma unroll
  for (int ct = 0; ct < 16; ++ct) {
    const int col = ct * 16 + m16;
    const float bv = bf2f(b3[col]);
#pragma unroll
    for (int r = 0; r < 4; ++r)
      Y[0][rbl + kg * 4 + r][col] = f2bf(fmaxf(acc[ct][r] + bv, 0.f));
  }
  __syncthreads();
#pragma unroll
  for (int ct = 0; ct < 16; ++ct) acc[ct] = z4;
  for (int k0 = 0; k0 < 256; k0 += 32) {
    bf16x8 a = *(const bf16x8*)(&Y[0][rbl + m16][k0 + kg * 8]);
#pragma unroll
    for (int ct = 0; ct < 16; ++ct)
      acc[ct] = MFMA16(a, ld8(w4T + (ct * 16 + m16) * 256 + k0 + kg * 8), acc[ct]);
  }
  float ssq[4] = {0.f, 0.f, 0.f, 0.f};
#pragma unroll
  for (int ct = 0; ct < 16; ++ct) {
    const int col = ct * 16 + m16;
    const float bv = bf2f(b4[col]);
#pragma unroll
    for (int r = 0; r < 4; ++r) {
      const int rl = rbl + kg * 4 + r;
      float v = fmaxf(acc[ct][r] + bv, 0.f) + bf2f(Y[1][rl][col]);
      ssq[r] += v * v;
      FT[(size_t)(rbg + kg * 4 + r) * 256 + col] = f2bf(v);
    }
  }
#pragma unroll
  for (int r = 0; r < 4; ++r) {
    float s = ssq[r];
#pragma unroll
    for (int mk = 1; mk < 16; mk <<= 1) s += __shfl_xor(s, mk, 64);
    if (m16 == 0) rs_ft[rbg + kg * 4 + r] = rsqrtf(s);
  }
}

// ---------------- fused features mega-kernel ----------------
__device__ void feat_body(const u16* __restrict__ X, const float* __restrict__ rscale,
                          const u16* __restrict__ PT, u16* __restrict__ OUT, int blk,
                          float* __restrict__ SBN) {
  __shared__ float cred[128];
  const int tid = threadIdx.x, lane = tid & 63, w = tid >> 6;
  const int m16 = lane & 15, kg = lane >> 4;
  const int rb = blk * 64 + w * 16;
  if (SBN) {
    if (tid < 128) cred[tid] = 0.f;
    __syncthreads();
  }
  const floatx4 z4 = {0.f, 0.f, 0.f, 0.f};
  floatx4 acc[8];
#pragma unroll
  for (int ct = 0; ct < 8; ++ct) acc[ct] = z4;
  for (int k0 = 0; k0 < 256; k0 += 32) {
    bf16x8 a = ld8(X + (size_t)(rb + m16) * 256 + k0 + kg * 8);
#pragma unroll
    for (int ct = 0; ct < 8; ++ct)
      acc[ct] = MFMA16(a, ld8(PT + (ct * 16 + m16) * 256 + k0 + kg * 8), acc[ct]);
  }
  float rs[4];
#pragma unroll
  for (int r = 0; r < 4; ++r) rs[r] = rscale[rb + kg * 4 + r];
#pragma unroll
  for (int ct = 0; ct < 8; ++ct) {
    float s = 0.f;
#pragma unroll
    for (int r = 0; r < 4; ++r) {
      float v = expf(acc[ct][r] * rs[r]);
      s += v;
      OUT[(size_t)(rb + kg * 4 + r) * 128 + ct * 16 + m16] = f2bf(v);
    }
    if (SBN) atomicAdd(&cred[ct * 16 + m16], s);
  }
  if (SBN) {
    __syncthreads();
    if (tid < 128) atomicAdd(&SBN[tid], cred[tid]);
  }
}

__device__ void gather_body(const int* __restrict__ text, const u16* __restrict__ TE,
                            const float* __restrict__ rs_term, const u16* __restrict__ PT,
                            u16* __restrict__ Btok, int blk) {
  const int tid = threadIdx.x, lane = tid & 63, w = tid >> 6;
  const int m16 = lane & 15, kg = lane >> 4;
  const int rb = blk * 64 + w * 16;
  const int ia = rb + m16;
  const int tok_a = text[(ia & 15) * 256 + (ia >> 4)];
  const floatx4 z4 = {0.f, 0.f, 0.f, 0.f};
  floatx4 acc[8];
#pragma unroll
  for (int ct = 0; ct < 8; ++ct) acc[ct] = z4;
  for (int k0 = 0; k0 < 256; k0 += 32) {
    bf16x8 a = ld8(TE + (size_t)tok_a * 256 + k0 + kg * 8);
#pragma unroll
    for (int ct = 0; ct < 8; ++ct)
      acc[ct] = MFMA16(a, ld8(PT + (ct * 16 + m16) * 256 + k0 + kg * 8), acc[ct]);
  }
  float rs[4];
#pragma unroll
  for (int r = 0; r < 4; ++r) {
    const int io = rb + kg * 4 + r;
    rs[r] = rs_term[text[(io & 15) * 256 + (io >> 4)]];
  }
#pragma unroll
  for (int ct = 0; ct < 8; ++ct)
#pragma unroll
    for (int r = 0; r < 4; ++r)
      Btok[(size_t)(rb + kg * 4 + r) * 128 + ct * 16 + m16] = f2bf(expf(acc[ct][r] * rs[r]));
}

// colsum: accumulate column sums of exp(c_term features) directly into SBT
// via device atomics (SBN pattern).
__device__ void colsum_body(const u16* __restrict__ X, const float* __restrict__ rscale,
                            const u16* __restrict__ PT, float* __restrict__ SBT, int blk) {
  __shared__ float cred2[128];
  const int tid = threadIdx.x, lane = tid & 63, w = tid >> 6;
  const int m16 = lane & 15, kg = lane >> 4;
  const int rb = blk * 64 + w * 16;
  if (tid < 128) cred2[tid] = 0.f;
  __syncthreads();
  const floatx4 z4 = {0.f, 0.f, 0.f, 0.f};
  floatx4 acc[8];
#pragma unroll
  for (int ct = 0; ct < 8; ++ct) acc[ct] = z4;
  for (int k0 = 0; k0 < 256; k0 += 32) {
    bf16x8 a = ld8(X + (size_t)(rb + m16) * 256 + k0 + kg * 8);
#pragma unroll
    for (int ct = 0; ct < 8; ++ct)
      acc[ct] = MFMA16(a, ld8(PT + (ct * 16 + m16) * 256 + k0 + kg * 8), acc[ct]);
  }
  float rs[4];
#pragma unroll
  for (int r = 0; r < 4; ++r) rs[r] = rscale[rb + kg * 4 + r];
#pragma unroll
  for (int ct = 0; ct < 8; ++ct) {
    float s = 0.f;
#pragma unroll
    for (int r = 0; r < 4; ++r) s += expf(acc[ct][r] * rs[r]);
    atomicAdd(&cred2[ct * 16 + m16], s);
  }
  __syncthreads();
  if (tid < 128) atomicAdd(&SBT[tid], cred2[tid]);
}

__global__ __launch_bounds__(256) void k_featall(
    const u16* __restrict__ c_state, const float* __restrict__ rs_state, u16* __restrict__ AxS,
    const u16* __restrict__ c_next, const float* __restrict__ rs_next, u16* __restrict__ ByN,
    float* __restrict__ SBN,
    const u16* __restrict__ ft, const float* __restrict__ rs_ft, u16* __restrict__ AxP,
    const int* __restrict__ text, const u16* __restrict__ c_term,
    const float* __restrict__ rs_term, u16* __restrict__ Btok,
    float* __restrict__ SBT, const u16* __restrict__ PT) {
  const int b = blockIdx.x;
  if (b < 64) feat_body(c_state, rs_state, PT, AxS, b, nullptr);
  else if (b < 128) feat_body(c_next, rs_next, PT, ByN, b - 64, SBN);
  else if (b < 192) feat_body(ft, rs_ft, PT, AxP, b - 128, nullptr);
  else if (b < 256) gather_body(text, c_term, rs_term, PT, Btok, b - 192);
  else colsum_body(c_term, rs_term, PT, SBT, b - 256);
}

// ---------------- per-state scalars ----------------
__global__ __launch_bounds__(256) void k_vecdots(
    const u16* __restrict__ AxS, const u16* __restrict__ AxP, const u16* __restrict__ ByN,
    const float* __restrict__ SBN, const float* __restrict__ SBT, const float* __restrict__ ex0,
    float* __restrict__ recip_r, float* __restrict__ recip_den,
    float* __restrict__ start_raw) {
  const int w = threadIdx.x >> 6, lane = threadIdx.x & 63;
  const int c = blockIdx.x * 4 + w;
  const int d = lane * 2;
  float a0 = bf2f(AxS[(size_t)c * 128 + d]), a1 = bf2f(AxS[(size_t)c * 128 + d + 1]);
  float t = wred64(a0 * SBN[d] + a1 * SBN[d + 1]);
  float p0 = bf2f(AxP[(size_t)c * 128 + d]), p1 = bf2f(AxP[(size_t)c * 128 + d + 1]);
  float p = wred64(p0 * SBT[d] + p1 * SBT[d + 1]);
  float y0 = bf2f(ByN[(size_t)c * 128 + d]), y1 = bf2f(ByN[(size_t)c * 128 + d + 1]);
  float s = wred64(y0 * ex0[d] + y1 * ex0[d + 1]);
  if (lane == 0) {
    recip_r[c] = 1.0f / t;
    recip_den[c] = 1.0f / p;
    start_raw[c] = s;
  }
}

// ---------------- fold/transpose 3 jobs ----------------
__global__ void k_foldT3(const u16* __restrict__ A0, const float* __restrict__ s0, u16* __restrict__ D0,
                         const u16* __restrict__ A1, const float* __restrict__ s1, u16* __restrict__ D1,
                         const u16* __restrict__ A2, u16* __restrict__ D2) {
  int i = blockIdx.x * 256 + threadIdx.x;
  int job = i >> 19;
  int r = i & 524287;
  int d = r >> 12, c = r & 4095;
  if (job == 0) D0[r] = f2bf(bf2f(A0[c * 128 + d]) * s0[c]);
  else if (job == 1) D1[r] = f2bf(bf2f(A1[c * 128 + d]) * s1[c]);
  else D2[r] = A2[c * 128 + d];
}

// ---------------- GEMM-1, LDS-pipelined; K-split x4 (1024-wide chunks) ----------------
__global__ __launch_bounds__(256) void k_gemm1(const u16* __restrict__ ByNT,
                                               const u16* __restrict__ AxS2T,
                                               const u16* __restrict__ AxP2T,
                                               float* __restrict__ Gp) {
  __shared__ __align__(16) u16 Ps[2][8192];
  const int tid = threadIdx.x, lane = tid & 63, w = tid >> 6;
  const int m16 = lane & 15, kg = lane >> 4;
  const int dp = blockIdx.x;
  const int kc = blockIdx.y;
  const int c0 = kc * 1024;
  const floatx4 z4 = {0.f, 0.f, 0.f, 0.f};
  floatx4 acc[2][8];
#pragma unroll
  for (int ct = 0; ct < 8; ++ct) { acc[0][ct] = z4; acc[1][ct] = z4; }
  bf16x8 Xr[2][4];
  bf16x8 Yr[2][2];

#define STAGE(P, cc) do {                                                     \
    const int cb_ = c0 + (cc) * 64;                                           \
    _Pragma("unroll")                                                         \
    for (int j_ = 0; j_ < 4; ++j_) {                                          \
      const u32 Lb_ = (u32)(j_ * 256 + tid) * 16u;                            \
      const u32 U_ = Lb_ ^ (((Lb_ >> 7) & 7u) << 4);                          \
      gload16(AxP2T + (size_t)(U_ >> 7) * 4096 + cb_ + ((U_ & 127u) >> 1),    \
              (char*)&Ps[P][0] + (j_ * 256 + w * 64) * 16);                   \
    }                                                                         \
  } while (0)

#define REGLOAD(P, cc) do {                                                   \
    const int cb_ = c0 + (cc) * 64 + kg * 8;                                  \
    Xr[P][0] = ld8(ByNT + (size_t)(32 * w + m16) * 4096 + cb_);               \
    Xr[P][1] = ld8(ByNT + (size_t)(32 * w + 16 + m16) * 4096 + cb_);          \
    Xr[P][2] = ld8(ByNT + (size_t)(32 * w + m16) * 4096 + cb_ + 32);          \
    Xr[P][3] = ld8(ByNT + (size_t)(32 * w + 16 + m16) * 4096 + cb_ + 32);     \
    if (dp < 128) {                                                           \
      Yr[P][0] = ld8(AxS2T + (size_t)dp * 4096 + cb_);                        \
      Yr[P][1] = ld8(AxS2T + (size_t)dp * 4096 + cb_ + 32);                   \
    }                                                                         \
  } while (0)

#define CHUNK(P) do {                                                         \
    _Pragma("unroll")                                                         \
    for (int kk_ = 0; kk_ < 2; ++kk_) {                                       \
      bf16x8 a0_, a1_;                                                        \
      if (dp < 128) {                                                         \
        bf16x8 yv_ = Yr[P][kk_];                                              \
        _Pragma("unroll")                                                     \
        for (int i_ = 0; i_ < 8; ++i_) {                                      \
          a0_[i_] = (__bf16)((float)Xr[P][kk_ * 2][i_] * (float)yv_[i_]);     \
          a1_[i_] = (__bf16)((float)Xr[P][kk_ * 2 + 1][i_] * (float)yv_[i_]); \
        }                                                                     \
      } else { a0_ = Xr[P][kk_ * 2]; a1_ = Xr[P][kk_ * 2 + 1]; }              \
      const int kb_ = (kk_ * 32 + kg * 8) * 2;                                \
      _Pragma("unroll")                                                       \
      for (int ct_ = 0; ct_ < 8; ++ct_) {                                     \
        const int e_ = ct_ * 16 + m16;                                        \
        bf16x8 bf_ = *(const bf16x8*)((const char*)&Ps[P][0] +                \
                       (u32)(((e_ << 7) + kb_) ^ ((e_ & 7) << 4)));           \
        acc[0][ct_] = MFMA16(a0_, bf_, acc[0][ct_]);                          \
        acc[1][ct_] = MFMA16(a1_, bf_, acc[1][ct_]);                          \
      }                                                                       \
    }                                                                         \
  } while (0)

  STAGE(0, 0);
  REGLOAD(0, 0);
#pragma unroll
  for (int cc = 0; cc < 16; ++cc) {
    __syncthreads();
    if (cc < 15) { STAGE((cc + 1) & 1, cc + 1); REGLOAD((cc + 1) & 1, cc + 1); }
    CHUNK(cc & 1);
  }

#undef STAGE
#undef REGLOAD
#undef CHUNK

  float* gp = Gp + (size_t)kc * 16512 * 128;
  const int rbase = dp * 128 + 32 * w;
#pragma unroll
  for (int t = 0; t < 2; ++t)
#pragma unroll
    for (int ct = 0; ct < 8; ++ct)
#pragma unroll
      for (int r = 0; r < 4; ++r)
        gp[(size_t)(rbase + t * 16 + kg * 4 + r) * 128 + ct * 16 + m16] = acc[t][ct][r];
}

// ---------------- reduce 4 K-chunk partials -> bf16 G (two layouts) ----------------
__global__ __launch_bounds__(256) void k_gred(const float* __restrict__ Gp,
                                              u16* __restrict__ G, u16* __restrict__ G2) {
  const int i = blockIdx.x * 256 + threadIdx.x;   // grid 8256 -> i < 2113536
  const size_t S = (size_t)16512 * 128;
  float s = 0.f;
#pragma unroll
  for (int k = 0; k < 4; ++k) s += Gp[i + k * S];
  u16 v = f2bf(s);
  G[i] = v;
  const int x = i >> 7, e = i & 127;
  if (x < 16384) {
    const int y = ((x & 127) << 7) | (x >> 7);
    G2[(size_t)y * 128 + e] = v;
  }
}

// ---------------- GEMM-2: linear grid padded to 136 columns so all y-blocks of
// one bx share an XCD class (w%8 == bx%8): each Gm/Gm2 slice is fetched once
// per XCD instead of 8x (round-13 FETCH=70MB was input re-fetch, not RMW).
__global__ __launch_bounds__(256) void k_gemm2(const u16* __restrict__ A, const u16* __restrict__ Gm,
                                               const u16* __restrict__ Gm2,
                                               u16* __restrict__ Bo, u16* __restrict__ Be) {
  __shared__ __align__(16) u16 ot[128][136];
  const int b = blockIdx.x;          // 0..4351 (136 x 32)
  const int bx = b % 136;
  if (bx >= 129) return;
  const int by = b / 136;            // 0..31
  const int tid = threadIdx.x, lane = tid & 63, w = tid >> 6;
  const int m16 = lane & 15, kg = lane >> 4;
  const int pass = by >> 4;          // 0 = odd-t, 1 = even-t
  if (pass == 1 && bx == 128) return;
  const int mb = (by & 15) * 128 + w * 32;   // q-space row base
  const int nb = bx * 128;
  const int off = pass ? 0 : 16;
  const int nt0 = 2 * mb + off + m16;
  const int nt1 = 2 * mb + 32 + off + m16;
  const u16* Gs = pass ? Gm2 : Gm;
  const floatx4 z4 = {0.f, 0.f, 0.f, 0.f};
  floatx4 acc[2][8];
#pragma unroll
  for (int rt = 0; rt < 2; ++rt)
#pragma unroll
    for (int ct = 0; ct < 8; ++ct) acc[rt][ct] = z4;
  for (int k0 = 0; k0 < 128; k0 += 32) {
    bf16x8 a0 = ld8(A + (size_t)nt0 * 128 + k0 + kg * 8);
    bf16x8 a1 = ld8(A + (size_t)nt1 * 128 + k0 + kg * 8);
#pragma unroll
    for (int ct = 0; ct < 8; ++ct) {
      bf16x8 bb = ld8(Gs + (size_t)(nb + ct * 16 + m16) * 128 + k0 + kg * 8);
      acc[0][ct] = MFMA16(a0, bb, acc[0][ct]);
      acc[1][ct] = MFMA16(a1, bb, acc[1][ct]);
    }
  }
  // stage tile in LDS
#pragma unroll
  for (int rt = 0; rt < 2; ++rt)
#pragma unroll
    for (int ct = 0; ct < 8; ++ct)
#pragma unroll
      for (int r = 0; r < 4; ++r)
        ot[w * 32 + rt * 16 + kg * 4 + r][ct * 16 + m16] = f2bf(acc[rt][ct][r]);
  __syncthreads();
  // full-line stores: 2048 uint4 chunks, 16 per row (256B contiguous)
  const int qbase = (by & 15) * 128;
  u16* Bp = pass ? Be : Bo;
  const size_t stride = pass ? 16384 : 16512;
#pragma unroll
  for (int c = tid; c < 2048; c += 256) {
    const int row = c >> 4, cc = (c & 15) * 8;
    *(uint4*)(Bp + (size_t)(qbase + row) * stride + nb + cc) =
        *(const uint4*)(&ot[row][cc]);
  }
}

// ---------------- pair products, LDS-staged ----------------
__global__ __launch_bounds__(256) void k_pairA(const u16* __restrict__ Bo,
                                               const u16* __restrict__ Be,
                                               u16* __restrict__ P01,
                                               u16* __restrict__ P23) {
  __shared__ __align__(16) u16 As[144 * 128];
  __shared__ __align__(16) u16 Bs[128 * 128];
  const int tid = threadIdx.x, lane = tid & 63, w = tid >> 6;
  const int m16 = lane & 15, kg = lane >> 4;
  const int q2 = blockIdx.x >> 1, which = blockIdx.x & 1;
  const int q1a = 2 * (q2 & ~15) + (q2 & 15);
  const int q1b = q1a + 16;
  const u16* Asrc = which ? Bo + (size_t)q1b * 16512 : Be + (size_t)q1a * 16384;
  const u16* Bsrc = which ? Be + (size_t)q1b * 16384 : Bo + (size_t)q1a * 16512;
  u16* dst = which ? P23 + (size_t)q2 * 16512 : P01 + (size_t)q2 * 16384;
  const int rmax = which ? 129 : 128;
#pragma unroll
  for (int it = 0; it < 9; ++it) {
    const u32 c = (u32)(it * 256 + tid);
    const u32 g = c ^ ((c >> 4) & 7u);
    gload16((const char*)Asrc + g * 16, (char*)As + (it * 256 + w * 64) * 16);
  }
#pragma unroll
  for (int it = 0; it < 8; ++it) {
    const u32 c = (u32)(it * 256 + tid);
    const u32 g = c ^ ((c >> 4) & 7u);
    gload16((const char*)Bsrc + g * 16, (char*)Bs + (it * 256 + w * 64) * 16);
  }
  asm volatile("s_waitcnt vmcnt(0)" ::: "memory");
  __syncthreads();
  const floatx4 z4 = {0.f, 0.f, 0.f, 0.f};
  for (int ti = w; ti < 72; ti += 4) {
    const int mi = ti / 8, ni = ti % 8;
    floatx4 acc = z4;
#pragma unroll
    for (int kk = 0; kk < 4; ++kk) {
      const int ar = mi * 16 + m16, br = ni * 16 + m16;
      const u32 ka = (u32)(ar * 256 + (kk * 32 + kg * 8) * 2) ^ (u32)((ar & 7) << 4);
      const u32 kb = (u32)(br * 256 + (kk * 32 + kg * 8) * 2) ^ (u32)((br & 7) << 4);
      acc = MFMA16(*(const bf16x8*)((const char*)As + ka),
                   *(const bf16x8*)((const char*)Bs + kb), acc);
    }
#pragma unroll
    for (int r = 0; r < 4; ++r) {
      const int row = mi * 16 + kg * 4 + r, col = ni * 16 + m16;
      if (row < rmax) dst[row * 128 + col] = f2bf(acc[r] * 4096.0f);
    }
  }
}

// ---------------- quad finish: D2[q2] = P23[q2] x P01[q2] (P23 aliases D2) ----------------
__global__ __launch_bounds__(256) void k_quadB(const u16* __restrict__ P23,
                                               const u16* __restrict__ P01,
                                               u16* __restrict__ D2) {
  __shared__ __align__(16) u16 As[144 * 128];
  __shared__ __align__(16) u16 Bs[128 * 128];
  const int tid = threadIdx.x, lane = tid & 63, w = tid >> 6;
  const int m16 = lane & 15, kg = lane >> 4;
  const int q2 = blockIdx.x;
  const u16* Asrc = P23 + (size_t)q2 * 16512;
  const u16* Bsrc = P01 + (size_t)q2 * 16384;
  u16* dst = D2 + (size_t)q2 * 16512;
#pragma unroll
  for (int it = 0; it < 9; ++it) {
    const u32 c = (u32)(it * 256 + tid);
    const u32 g = c ^ ((c >> 4) & 7u);
    gload16((const char*)Asrc + g * 16, (char*)As + (it * 256 + w * 64) * 16);
  }
#pragma unroll
  for (int it = 0; it < 8; ++it) {
    const u32 c = (u32)(it * 256 + tid);
    const u32 g = c ^ ((c >> 4) & 7u);
    gload16((const char*)Bsrc + g * 16, (char*)Bs + (it * 256 + w * 64) * 16);
  }
  asm volatile("s_waitcnt vmcnt(0)" ::: "memory");
  __syncthreads();
  const floatx4 z4 = {0.f, 0.f, 0.f, 0.f};
  for (int ti = w; ti < 72; ti += 4) {
    const int mi = ti / 8, ni = ti % 8;
    floatx4 acc = z4;
#pragma unroll
    for (int kk = 0; kk < 4; ++kk) {
      const int ar = mi * 16 + m16, br = ni * 16 + m16;
      const u32 ka = (u32)(ar * 256 + (kk * 32 + kg * 8) * 2) ^ (u32)((ar & 7) << 4);
      const u32 kb = (u32)(br * 256 + (kk * 32 + kg * 8) * 2) ^ (u32)((br & 7) << 4);
      acc = MFMA16(*(const bf16x8*)((const char*)As + ka),
                   *(const bf16x8*)((const char*)Bs + kb), acc);
    }
#pragma unroll
    for (int r = 0; r < 4; ++r) {
      const int row = mi * 16 + kg * 4 + r, col = ni * 16 + m16;
      if (row < 129) dst[row * 128 + col] = f2bf(acc[r]);
    }
  }
}

// ---------------- scan: 16 blocks, 64 steps over composed quads (R4 structure).
__global__ __launch_bounds__(256) void k_scan2(const u16* __restrict__ Bm,
                                               const float* __restrict__ ex0,
                                               float* __restrict__ evp) {
  __shared__ __align__(16) u16 vb[2][128];
  const int tid = threadIdx.x, lane = tid & 63, w = tid >> 6;
  const int m16 = lane & 15, kg = lane >> 4;
  const int n = blockIdx.x;
  const int g0 = w * 2, g1 = w * 2 + 1;
  const int offA0 = (g0 * 16 + m16) * 128 + kg * 8;
  const int offA1 = (g1 * 16 + m16) * 128 + kg * 8;
  const int offS = 16384 + lane * 2;
  const floatx4 z4 = {0.f, 0.f, 0.f, 0.f};

  if (tid < 128) vb[0][tid] = f2bf(ex0[tid]);
  int esum = 0;
  float finlog = 0.f;

  bf16x8 A0[2][4], A1[2][4], A2[2][4];
  u32 s0 = 0, s1 = 0, s2 = 0;

#define PREF(t, A, S) do {                                                   \
    const u16* rp_ = Bm + (size_t)((((t) << 4) | n)) * 16512;                \
    A[0][0] = ld8(rp_ + offA0);      A[0][1] = ld8(rp_ + offA0 + 32);        \
    A[0][2] = ld8(rp_ + offA0 + 64); A[0][3] = ld8(rp_ + offA0 + 96);        \
    A[1][0] = ld8(rp_ + offA1);      A[1][1] = ld8(rp_ + offA1 + 32);        \
    A[1][2] = ld8(rp_ + offA1 + 64); A[1][3] = ld8(rp_ + offA1 + 96);        \
    S = *(const u32*)(rp_ + offS);                                           \
  } while (0)

#define STEP(t, A, S) do {                                                   \
    if ((t) < 62)       asm volatile("s_waitcnt vmcnt(18)" ::: "memory");    \
    else if ((t) == 62) asm volatile("s_waitcnt vmcnt(9)" ::: "memory");     \
    else                asm volatile("s_waitcnt vmcnt(0)" ::: "memory");     \
    asm volatile("s_waitcnt lgkmcnt(0)" ::: "memory");                       \
    __builtin_amdgcn_s_barrier();                                            \
    const u16* vc_ = vb[(t) & 1];                                            \
    u32 vpair_ = *(const u32*)(vc_ + lane * 2);                              \
    float sdot_ = bf2f((u16)(vpair_ & 0xFFFFu)) * bf2f((u16)((S) & 0xFFFFu)) \
                + bf2f((u16)(vpair_ >> 16)) * bf2f((u16)((S) >> 16));        \
    _Pragma("unroll")                                                        \
    for (int of_ = 1; of_ < 64; of_ <<= 1) sdot_ += __shfl_xor(sdot_, of_, 64); \
    if ((t) == 63) {                                                         \
      finlog = logf(sdot_);                                                  \
    } else {                                                                 \
      bf16x8 b0_ = *(const bf16x8*)(vc_ + kg * 8);                           \
      bf16x8 b1_ = *(const bf16x8*)(vc_ + 32 + kg * 8);                      \
      bf16x8 b2_ = *(const bf16x8*)(vc_ + 64 + kg * 8);                      \
      bf16x8 b3_ = *(const bf16x8*)(vc_ + 96 + kg * 8);                      \
      floatx4 ac0_ = z4, ac1_ = z4;                                          \
      ac0_ = MFMA16(A[0][0], b0_, ac0_); ac1_ = MFMA16(A[1][0], b0_, ac1_);  \
      ac0_ = MFMA16(A[0][1], b1_, ac0_); ac1_ = MFMA16(A[1][1], b1_, ac1_);  \
      ac0_ = MFMA16(A[0][2], b2_, ac0_); ac1_ = MFMA16(A[1][2], b2_, ac1_);  \
      ac0_ = MFMA16(A[0][3], b3_, ac0_); ac1_ = MFMA16(A[1][3], b3_, ac1_);  \
      u32 sb_; __builtin_memcpy(&sb_, &sdot_, 4);                            \
      int e_ = (int)((sb_ >> 23) & 255u) - 127;                              \
      esum += e_;                                                            \
      float scale_; { u32 se_ = (u32)(127 - e_) << 23;                       \
                      __builtin_memcpy(&scale_, &se_, 4); }                  \
      if (m16 == 0) {                                                        \
        u16 p0_[4], p1_[4];                                                  \
        _Pragma("unroll")                                                    \
        for (int r_ = 0; r_ < 4; ++r_) {                                     \
          p0_[r_] = f2bf(ac0_[r_] * scale_);                                 \
          p1_[r_] = f2bf(ac1_[r_] * scale_);                                 \
        }                                                                    \
        u16* dst_ = vb[((t) + 1) & 1];                                       \
        uint2 q0_, q1_;                                                      \
        __builtin_memcpy(&q0_, p0_, 8); __builtin_memcpy(&q1_, p1_, 8);      \
        *(uint2*)(dst_ + g0 * 16 + kg * 4) = q0_;                            \
        *(uint2*)(dst_ + g1 * 16 + kg * 4) = q1_;                            \
      }                                                                      \
    }                                                                        \
    if ((t) + 3 < 64) PREF((t) + 3, A, S);                                   \
  } while (0)

  PREF(0, A0, s0);
  PREF(1, A1, s1);
  PREF(2, A2, s2);

  for (int tt = 0; tt < 63; tt += 3) {
    STEP(tt, A0, s0);
    STEP(tt + 1, A1, s1);
    STEP(tt + 2, A2, s2);
  }
  STEP(63, A0, s0);

#undef PREF
#undef STEP

  if (tid == 0) evp[n] = finlog + 0.6931471805599453f * (float)(esum - 1536);
}

// ---------------- final ----------------
__global__ void k_final(const float* __restrict__ evp, const float* __restrict__ SBN,
                        const float* __restrict__ ex0, const int* __restrict__ flag,
                        u16* __restrict__ outp) {
  if (threadIdx.x == 0 && blockIdx.x == 0) {
    float ev = 0.f;
    for (int i = 0; i < 16; ++i) ev += evp[i];
    float ssum = 0.f;
    for (int d = 0; d < 128; ++d) ssum += SBN[d] * ex0[d];
    ev -= 16.0f * logf(ssum);
    store_final(outp, ev, *flag);
  }
}

extern "C" void kernel_launch(void* const* d_in, const int* in_sizes, int n_in,
                              void* d_out, int out_size, void* d_ws, size_t ws_size,
                              hipStream_t stream) {
  (void)out_size;
  u16* outp = (u16*)d_out;
  if (n_in != 26 || in_sizes[25] != 128 * 256) {
    k_sentinel<<<1, 1, 0, stream>>>(outp, 5000.0f + (float)n_in);
    return;
  }
  const int* text = (const int*)d_in[0];

  char* base = (char*)d_ws;
  size_t off = 0;
  auto take = [&](size_t bytes) -> char* {
    char* p = base + off;
    off = (off + bytes + 255) & ~(size_t)255;
    return p;
  };
  int* flag = (int*)take(256);
  u16* c_se   = (u16*)take(256 * 2);
  u16* c_w[18];
  for (int i = 0; i < 18; ++i) c_w[i] = (u16*)take(((i & 1) ? 256 : 65536) * 2);
  u16* c_state = (u16*)take((size_t)1048576 * 2);
  u16* c_next  = (u16*)take((size_t)1048576 * 2);
  u16* c_pre   = (u16*)take((size_t)1048576 * 2);
  u16* c_term  = (u16*)take((size_t)8192000 * 2);
  u16* c_proj  = (u16*)take((size_t)32768 * 2);
  u16* projT  = (u16*)take(128 * 256 * 2);
  u16* twT1   = (u16*)take(65536 * 2);
  u16* twT2   = (u16*)take(65536 * 2);
  u16* twT3   = (u16*)take(65536 * 2);
  u16* twT4   = (u16*)take(65536 * 2);
  u16* ft     = (u16*)take((size_t)4096 * 256 * 2);
  float* rs_state = (float*)take(4096 * 4);
  float* rs_next  = (float*)take(4096 * 4);
  float* rs_ft    = (float*)take(4096 * 4);
  float* rs_term  = (float*)take(32000 * 4);
  u16* AxS    = (u16*)take((size_t)4096 * 128 * 2);
  u16* ByN    = (u16*)take((size_t)4096 * 128 * 2);
  u16* AxP    = (u16*)take((size_t)4096 * 128 * 2);
  u16* Btok   = (u16*)take((size_t)4096 * 128 * 2);
  u16* AxS2T  = (u16*)take((size_t)128 * 4096 * 2);
  u16* AxP2T  = (u16*)take((size_t)128 * 4096 * 2);
  u16* ByNT   = (u16*)take((size_t)128 * 4096 * 2);
  u16* Gm     = (u16*)take((size_t)16512 * 128 * 2);
  u16* Gm2    = (u16*)take((size_t)16384 * 128 * 2);
  u16* Bo     = (u16*)take((size_t)2049 * 16512 * 2);   // odd-t matrices, out-major
  u16* Be     = (u16*)take((size_t)2049 * 16384 * 2);   // even-t matrices, in-major
  u16* D2buf  = (u16*)take((size_t)1025 * 16512 * 2);   // P23 then composed quads
  u16* P01buf = (u16*)take((size_t)1025 * 16384 * 2);   // pair products 01
  float* recip_r   = (float*)take(4096 * 4);
  float* recip_den = (float*)take(4096 * 4);
  float* start_raw = (float*)take(4096 * 4);
  float* ex0       = (float*)take(132 * 4);
  float* zreg = (float*)take(2048);   // SBN | SBT (zeroed)
  float* SBN = zreg, *SBT = zreg + 128;
  float* evp = (float*)take(64);
  // Gpart (4 x 16512 x 128 f32 = 33.8 MB) aliases Bo (67.7 MB): gemm1 writes
  // it, gred consumes it, then gemm2 overwrites Bo. Stream-ordered -> safe.
  float* Gpart = (float*)Bo;

  const float ws_mb = (float)(ws_size >> 20) > 900.f ? 900.f : (float)(ws_size >> 20);
  if (off > ws_size) {
    k_sentinel<<<1, 1, 0, stream>>>(outp, 1000.0f + ws_mb);
    return;
  }

  k_detect<<<1, 64, 0, stream>>>((const u32*)d_in[25], flag);
  k_sentinel<<<1, 1, 0, stream>>>(outp, -7777.0f);  // breadcrumb
  hipMemsetAsync(zreg, 0, 2048, stream);

  // fused convert: 24 jobs
  CvtJobs cj;
  int cb_ = 0, cjn = 0;
  auto addcvt = [&](const void* s, u16* d, int n) {
    cj.src[cjn] = s; cj.dst[cjn] = d; cj.n[cjn] = n;
    cj.bstart[cjn] = cb_; cb_ += (n + 4095) / 4096; ++cjn;
  };
  addcvt(d_in[2], c_se, 256);
  for (int i = 0; i < 18; ++i) addcvt(d_in[3 + i], c_w[i], (i & 1) ? 256 : 65536);
  addcvt(d_in[21], c_state, 1048576);
  addcvt(d_in[22], c_next, 1048576);
  addcvt(d_in[23], c_pre, 1048576);
  addcvt(d_in[24], c_term, 8192000);
  addcvt(d_in[25], c_proj, 32768);
  cj.bstart[24] = cb_;
  k_cvt_all<<<cb_, 256, 0, stream>>>(cj, flag);

  // fused transposes: 5 jobs
  TrJobs tj;
  tj.src[0] = c_proj; tj.dst[0] = projT; tj.R[0] = 256; tj.C[0] = 128;
  tj.src[1] = c_w[10]; tj.dst[1] = twT1; tj.R[1] = 256; tj.C[1] = 256;
  tj.src[2] = c_w[12]; tj.dst[2] = twT2; tj.R[2] = 256; tj.C[2] = 256;
  tj.src[3] = c_w[14]; tj.dst[3] = twT3; tj.R[3] = 256; tj.C[3] = 256;
  tj.src[4] = c_w[16]; tj.dst[4] = twT4; tj.R[4] = 256; tj.C[4] = 256;
  int tb = 0;
  for (int j = 0; j < 5; ++j) { tj.bstart[j] = tb; tb += (tj.R[j] * tj.C[j]) / 1024; }
  tj.bstart[5] = tb;
  k_transpose_all<<<tb, 256, 0, stream>>>(tj);

  // fused rownorm: state, next, term
  RnJobs rj;
  rj.X[0] = c_state; rj.out[0] = rs_state; rj.rows[0] = 4096;
  rj.X[1] = c_next;  rj.out[1] = rs_next;  rj.rows[1] = 4096;
  rj.X[2] = c_term;  rj.out[2] = rs_term;  rj.rows[2] = 32000;
  rj.bstart[0] = 0; rj.bstart[1] = 1024; rj.bstart[2] = 2048; rj.bstart[3] = 10048;
  k_rownorm_all<<<10048, 256, 0, stream>>>(rj);

  k_start<<<1, 256, 0, stream>>>(c_se, c_w[0], c_w[1], c_w[2], c_w[3], c_w[4], c_w[5],
                                 c_w[6], c_w[7], c_w[8], c_w[9], c_proj, ex0);
  k_mlp<<<64, 256, 0, stream>>>(c_pre, twT1, c_w[11], twT2, c_w[13], twT3, c_w[15],
                                twT4, c_w[17], ft, rs_ft);
  k_featall<<<756, 256, 0, stream>>>(c_state, rs_state, AxS, c_next, rs_next, ByN, SBN,
                                     ft, rs_ft, AxP, text, c_term, rs_term, Btok,
                                     SBT, projT);
  k_vecdots<<<1024, 256, 0, stream>>>(AxS, AxP, ByN, SBN, SBT, ex0, recip_r, recip_den,
                                      start_raw);
  k_foldT3<<<6144, 256, 0, stream>>>(AxS, recip_r, AxS2T, AxP, recip_den, AxP2T, ByN, ByNT);
  k_gemm1<<<dim3(129, 4), 256, 0, stream>>>(ByNT, AxS2T, AxP2T, Gpart);
  k_gred<<<8256, 256, 0, stream>>>(Gpart, Gm, Gm2);
  k_gemm2<<<4352, 256, 0, stream>>>(Btok, Gm, Gm2, Bo, Be);
  k_pairA<<<2048, 256, 0, stream>>>(Bo, Be, P01buf, D2buf);
  k_quadB<<<1024, 256, 0, stream>>>(D2buf, P01buf, D2buf);
  k_scan2<<<16, 256, 0, stream>>>(D2buf, ex0, evp);
  k_final<<<1, 64, 0, stream>>>(evp, SBN, ex0, flag, outp);
}

// Round 16
// 615.132 us; speedup vs baseline: 1.0141x; 1.0141x over previous
//
#include <hip/hip_runtime.h>
#include <math.h>

typedef unsigned short u16;
typedef unsigned int u32;
typedef __bf16 bf16x8 __attribute__((ext_vector_type(8)));
typedef float floatx4 __attribute__((ext_vector_type(4)));

#define MFMA16(a, b, c) __builtin_amdgcn_mfma_f32_16x16x32_bf16((a), (b), (c), 0, 0, 0)

__device__ __forceinline__ float bf2f(u16 u) {
  u32 x = ((u32)u) << 16; float f; __builtin_memcpy(&f, &x, 4); return f;
}
__device__ __forceinline__ u16 f2bf(float f) {
  u32 x; __builtin_memcpy(&x, &f, 4);
  return (u16)((x + 0x7FFFu + ((x >> 16) & 1u)) >> 16);  // RNE
}
__device__ __forceinline__ void store_dual(u16* outp, float v) {
  u32 h = (u32)f2bf(v);
  *(u32*)outp = (h << 16) | h;
}
__device__ __forceinline__ bf16x8 ld8(const u16* p) { return *(const bf16x8*)p; }

__device__ __forceinline__ void gload16(const void* g, void* l) {
  __builtin_amdgcn_global_load_lds((const __attribute__((address_space(1))) u32*)g,
                                   (__attribute__((address_space(3))) u32*)l, 16, 0, 0);
}

__device__ __forceinline__ float wred64(float v) {
#pragma unroll
  for (int off = 32; off > 0; off >>= 1) v += __shfl_down(v, off, 64);
  return v;
}

__device__ __forceinline__ void store_final(u16* outp, float ev, int flag) {
  if (!(ev == ev) || fabsf(ev) > 1e37f) ev = -12345.0f - 1000.0f * (float)flag;
  if (flag) *(float*)outp = ev;
  else outp[0] = f2bf(ev);
}

// ---------------- diagnostics ----------------
__global__ void k_sentinel(u16* outp, float v) {
  if (threadIdx.x == 0 && blockIdx.x == 0) store_dual(outp, v);
}

// ---------------- input dtype detect: flag=1 if f32, 0 if bf16 ----------------
__global__ void k_detect(const u32* __restrict__ raw, int* __restrict__ flag) {
  if (threadIdx.x == 0 && blockIdx.x == 0) {
    int outliers = 0;
    for (int i = 0; i < 64; ++i) {
      u32 lo = raw[i] & 0xFFFFu;
      int e = (int)((lo >> 7) & 0xFF);
      if (e < 100 || e > 150) ++outliers;
    }
    *flag = (outliers > 16) ? 1 : 0;
  }
}

// ---------------- fused dtype-aware convert (24 jobs, one launch) ----------------
struct CvtJobs {
  const void* src[24];
  u16* dst[24];
  int n[24];
  int bstart[25];
};
__global__ __launch_bounds__(256) void k_cvt_all(CvtJobs a, const int* __restrict__ flag) {
  const int b = blockIdx.x, tid = threadIdx.x;
  int j = 0;
  while (b >= a.bstart[j + 1]) ++j;
  const int base = (b - a.bstart[j]) * 4096;
  const int n = a.n[j];
  if (*flag) {
    const float* s = (const float*)a.src[j];
    u16* d = a.dst[j];
    for (int i0 = base + tid * 4; i0 < base + 4096 && i0 < n; i0 += 1024) {
      float4 v = *(const float4*)(s + i0);
      u16 o[4] = {f2bf(v.x), f2bf(v.y), f2bf(v.z), f2bf(v.w)};
      __builtin_memcpy(d + i0, o, 8);
    }
  } else {
    const u16* s = (const u16*)a.src[j];
    u16* d = a.dst[j];
    for (int i0 = base + tid * 4; i0 < base + 4096 && i0 < n; i0 += 1024)
      *(uint2*)(d + i0) = *(const uint2*)(s + i0);
  }
}

// ---------------- fused transpose (5 jobs) ----------------
struct TrJobs {
  const u16* src[5];
  u16* dst[5];
  int R[5], C[5];
  int bstart[6];
};
__global__ __launch_bounds__(256) void k_transpose_all(TrJobs a) {
  const int b = blockIdx.x, tid = threadIdx.x;
  int j = 0;
  while (b >= a.bstart[j + 1]) ++j;
  const int base = (b - a.bstart[j]) * 1024;
  const int R = a.R[j], C = a.C[j], tot = R * C;
  const u16* in = a.src[j];
  u16* out = a.dst[j];
#pragma unroll
  for (int k = 0; k < 4; ++k) {
    int i = base + tid + k * 256;
    if (i < tot) { int r = i / C, c = i - r * C; out[c * R + r] = in[i]; }
  }
}

// ---------------- fused per-row 1/||x|| (3 jobs) ----------------
struct RnJobs {
  const u16* X[3];
  float* out[3];
  int rows[3];
  int bstart[4];
};
__global__ __launch_bounds__(256) void k_rownorm_all(RnJobs a) {
  const int b = blockIdx.x;
  int j = 0;
  while (b >= a.bstart[j + 1]) ++j;
  const int w = threadIdx.x >> 6, lane = threadIdx.x & 63;
  const int row = (b - a.bstart[j]) * 4 + w;
  if (row >= a.rows[j]) return;
  const u16* p = a.X[j] + (size_t)row * 256 + lane * 4;
  float s = 0.f;
#pragma unroll
  for (int i = 0; i < 4; ++i) { float v = bf2f(p[i]); s += v * v; }
  s = wred64(s);
  if (lane == 0) a.out[j][row] = rsqrtf(s);
}

// ---------------- start-vector MLP (1 block) -> ex0[128] ----------------
__global__ __launch_bounds__(256) void k_start(
    const u16* __restrict__ se,
    const u16* __restrict__ sw0, const u16* __restrict__ sb0,
    const u16* __restrict__ sw1, const u16* __restrict__ sb1,
    const u16* __restrict__ sw2, const u16* __restrict__ sb2,
    const u16* __restrict__ sw3, const u16* __restrict__ sb3,
    const u16* __restrict__ sw4, const u16* __restrict__ sb4,
    const u16* __restrict__ proj, float* __restrict__ ex0) {
  __shared__ float xa[256], xb[256], xc[256], red[256];
  const int tid = threadIdx.x;
  xa[tid] = bf2f(se[tid]);
  __syncthreads();
  float acc = bf2f(sb0[tid]);
  for (int k = 0; k < 256; ++k) acc += xa[k] * bf2f(sw0[k * 256 + tid]);
  xb[tid] = acc;
  __syncthreads();
  acc = bf2f(sb1[tid]);
  for (int k = 0; k < 256; ++k) acc += xb[k] * bf2f(sw1[k * 256 + tid]);
  xc[tid] = fmaxf(acc, 0.f);
  __syncthreads();
  acc = bf2f(sb2[tid]);
  for (int k = 0; k < 256; ++k) acc += xc[k] * bf2f(sw2[k * 256 + tid]);
  xa[tid] = fmaxf(acc, 0.f) + xb[tid];
  __syncthreads();
  acc = bf2f(sb3[tid]);
  for (int k = 0; k < 256; ++k) acc += xa[k] * bf2f(sw3[k * 256 + tid]);
  xc[tid] = fmaxf(acc, 0.f);
  __syncthreads();
  acc = bf2f(sb4[tid]);
  for (int k = 0; k < 256; ++k) acc += xc[k] * bf2f(sw4[k * 256 + tid]);
  xb[tid] = fmaxf(acc, 0.f) + xa[tid];
  __syncthreads();
  red[tid] = xb[tid] * xb[tid];
  __syncthreads();
  for (int s = 128; s > 0; s >>= 1) {
    if (tid < s) red[tid] += red[tid + s];
    __syncthreads();
  }
  const float rs = rsqrtf(red[0]);
  xa[tid] = xb[tid] * rs;
  __syncthreads();
  if (tid < 128) {
    float a = 0.f;
    for (int k = 0; k < 256; ++k) a += xa[k] * bf2f(proj[k * 128 + tid]);
    ex0[tid] = expf(a);
  }
}

// ---------------- preterminal MLP + fused rs_ft ----------------
__global__ __launch_bounds__(256) void k_mlp(
    const u16* __restrict__ X0,
    const u16* __restrict__ w1T, const u16* __restrict__ b1,
    const u16* __restrict__ w2T, const u16* __restrict__ b2,
    const u16* __restrict__ w3T, const u16* __restrict__ b3,
    const u16* __restrict__ w4T, const u16* __restrict__ b4,
    u16* __restrict__ FT, float* __restrict__ rs_ft) {
  __shared__ __align__(16) u16 Y[2][64][264];
  const int tid = threadIdx.x, lane = tid & 63, w = tid >> 6;
  const int m16 = lane & 15, kg = lane >> 4;
  const int rbl = w * 16;
  const int rbg = blockIdx.x * 64 + rbl;
  const floatx4 z4 = {0.f, 0.f, 0.f, 0.f};
  floatx4 acc[16];

#pragma unroll
  for (int ct = 0; ct < 16; ++ct) acc[ct] = z4;
  for (int k0 = 0; k0 < 256; k0 += 32) {
    bf16x8 a = ld8(X0 + (size_t)(rbg + m16) * 256 + k0 + kg * 8);
#pragma unroll
    for (int ct = 0; ct < 16; ++ct)
      acc[ct] = MFMA16(a, ld8(w1T + (ct * 16 + m16) * 256 + k0 + kg * 8), acc[ct]);
  }
#pragma unroll
  for (int ct = 0; ct < 16; ++ct) {
    const int col = ct * 16 + m16;
    const float bv = bf2f(b1[col]);
#pragma unroll
    for (int r = 0; r < 4; ++r)
      Y[0][rbl + kg * 4 + r][col] = f2bf(fmaxf(acc[ct][r] + bv, 0.f));
  }
  __syncthreads();
#pragma unroll
  for (int ct = 0; ct < 16; ++ct) acc[ct] = z4;
  for (int k0 = 0; k0 < 256; k0 += 32) {
    bf16x8 a = *(const bf16x8*)(&Y[0][rbl + m16][k0 + kg * 8]);
#pragma unroll
    for (int ct = 0; ct < 16; ++ct)
      acc[ct] = MFMA16(a, ld8(w2T + (ct * 16 + m16) * 256 + k0 + kg * 8), acc[ct]);
  }
#pragma unroll
  for (int ct = 0; ct < 16; ++ct) {
    const int col = ct * 16 + m16;
    const float bv = bf2f(b2[col]);
#pragma unroll
    for (int r = 0; r < 4; ++r) {
      const int gr = rbg + kg * 4 + r;
      float v = fmaxf(acc[ct][r] + bv, 0.f) + bf2f(X0[(size_t)gr * 256 + col]);
      Y[1][rbl + kg * 4 + r][col] = f2bf(v);
    }
  }
  __syncthreads();
#pragma unroll
  for (int ct = 0; ct < 16; ++ct) acc[ct] = z4;
  for (int k0 = 0; k0 < 256; k0 += 32) {
    bf16x8 a = *(const bf16x8*)(&Y[1][rbl + m16][k0 + kg * 8]);
#pragma unroll
    for (int ct = 0; ct < 16; ++ct)
      acc[ct] = MFMA16(a, ld8(w3T + (ct * 16 + m16) * 256 + k0 + kg * 8), acc[ct]);
  }
#pragma unroll
  for (int ct = 0; ct < 16; ++ct) {
    const int col = ct * 16 + m16;
    const float bv = bf2f(b3[col]);
#pragma unroll
    for (int r = 0; r < 4; ++r)
      Y[0][rbl + kg * 4 + r][col] = f2bf(fmaxf(acc[ct][r] + bv, 0.f));
  }
  __syncthreads();
#pragma unroll
  for (int ct = 0; ct < 16; ++ct) acc[ct] = z4;
  for (int k0 = 0; k0 < 256; k0 += 32) {
    bf16x8 a = *(const bf16x8*)(&Y[0][rbl + m16][k0 + kg * 8]);
#pragma unroll
    for (int ct = 0; ct < 16; ++ct)
      acc[ct] = MFMA16(a, ld8(w4T + (ct * 16 + m16) * 256 + k0 + kg * 8), acc[ct]);
  }
  float ssq[4] = {0.f, 0.f, 0.f, 0.f};
#pragma unroll
  for (int ct = 0; ct < 16; ++ct) {
    const int col = ct * 16 + m16;
    const float bv = bf2f(b4[col]);
#pragma unroll
    for (int r = 0; r < 4; ++r) {
      const int rl = rbl + kg * 4 + r;
      float v = fmaxf(acc[ct][r] + bv, 0.f) + bf2f(Y[1][rl][col]);
      ssq[r] += v * v;
      FT[(size_t)(rbg + kg * 4 + r) * 256 + col] = f2bf(v);
    }
  }
#pragma unroll
  for (int r = 0; r < 4; ++r) {
    float s = ssq[r];
#pragma unroll
    for (int mk = 1; mk < 16; mk <<= 1) s += __shfl_xor(s, mk, 64);
    if (m16 == 0) rs_ft[rbg + kg * 4 + r] = rsqrtf(s);
  }
}

// ---------------- fused features mega-kernel ----------------
__device__ void feat_body(const u16* __restrict__ X, const float* __restrict__ rscale,
                          const u16* __restrict__ PT, u16* __restrict__ OUT, int blk,
                          float* __restrict__ SBN) {
  __shared__ float cred[128];
  const int tid = threadIdx.x, lane = tid & 63, w = tid >> 6;
  const int m16 = lane & 15, kg = lane >> 4;
  const int rb = blk * 64 + w * 16;
  if (SBN) {
    if (tid < 128) cred[tid] = 0.f;
    __syncthreads();
  }
  const floatx4 z4 = {0.f, 0.f, 0.f, 0.f};
  floatx4 acc[8];
#pragma unroll
  for (int ct = 0; ct < 8; ++ct) acc[ct] = z4;
  for (int k0 = 0; k0 < 256; k0 += 32) {
    bf16x8 a = ld8(X + (size_t)(rb + m16) * 256 + k0 + kg * 8);
#pragma unroll
    for (int ct = 0; ct < 8; ++ct)
      acc[ct] = MFMA16(a, ld8(PT + (ct * 16 + m16) * 256 + k0 + kg * 8), acc[ct]);
  }
  float rs[4];
#pragma unroll
  for (int r = 0; r < 4; ++r) rs[r] = rscale[rb + kg * 4 + r];
#pragma unroll
  for (int ct = 0; ct < 8; ++ct) {
    float s = 0.f;
#pragma unroll
    for (int r = 0; r < 4; ++r) {
      float v = expf(acc[ct][r] * rs[r]);
      s += v;
      OUT[(size_t)(rb + kg * 4 + r) * 128 + ct * 16 + m16] = f2bf(v);
    }
    if (SBN) atomicAdd(&cred[ct * 16 + m16], s);
  }
  if (SBN) {
    __syncthreads();
    if (tid < 128) atomicAdd(&SBN[tid], cred[tid]);
  }
}

__device__ void gather_body(const int* __restrict__ text, const u16* __restrict__ TE,
                            const float* __restrict__ rs_term, const u16* __restrict__ PT,
                            u16* __restrict__ Btok, int blk) {
  const int tid = threadIdx.x, lane = tid & 63, w = tid >> 6;
  const int m16 = lane & 15, kg = lane >> 4;
  const int rb = blk * 64 + w * 16;
  const int ia = rb + m16;
  const int tok_a = text[(ia & 15) * 256 + (ia >> 4)];
  const floatx4 z4 = {0.f, 0.f, 0.f, 0.f};
  floatx4 acc[8];
#pragma unroll
  for (int ct = 0; ct < 8; ++ct) acc[ct] = z4;
  for (int k0 = 0; k0 < 256; k0 += 32) {
    bf16x8 a = ld8(TE + (size_t)tok_a * 256 + k0 + kg * 8);
#pragma unroll
    for (int ct = 0; ct < 8; ++ct)
      acc[ct] = MFMA16(a, ld8(PT + (ct * 16 + m16) * 256 + k0 + kg * 8), acc[ct]);
  }
  float rs[4];
#pragma unroll
  for (int r = 0; r < 4; ++r) {
    const int io = rb + kg * 4 + r;
    rs[r] = rs_term[text[(io & 15) * 256 + (io >> 4)]];
  }
#pragma unroll
  for (int ct = 0; ct < 8; ++ct)
#pragma unroll
    for (int r = 0; r < 4; ++r)
      Btok[(size_t)(rb + kg * 4 + r) * 128 + ct * 16 + m16] = f2bf(expf(acc[ct][r] * rs[r]));
}

// colsum: accumulate column sums of exp(c_term features) directly into SBT
// via device atomics (SBN pattern).
__device__ void colsum_body(const u16* __restrict__ X, const float* __restrict__ rscale,
                            const u16* __restrict__ PT, float* __restrict__ SBT, int blk) {
  __shared__ float cred2[128];
  const int tid = threadIdx.x, lane = tid & 63, w = tid >> 6;
  const int m16 = lane & 15, kg = lane >> 4;
  const int rb = blk * 64 + w * 16;
  if (tid < 128) cred2[tid] = 0.f;
  __syncthreads();
  const floatx4 z4 = {0.f, 0.f, 0.f, 0.f};
  floatx4 acc[8];
#pragma unroll
  for (int ct = 0; ct < 8; ++ct) acc[ct] = z4;
  for (int k0 = 0; k0 < 256; k0 += 32) {
    bf16x8 a = ld8(X + (size_t)(rb + m16) * 256 + k0 + kg * 8);
#pragma unroll
    for (int ct = 0; ct < 8; ++ct)
      acc[ct] = MFMA16(a, ld8(PT + (ct * 16 + m16) * 256 + k0 + kg * 8), acc[ct]);
  }
  float rs[4];
#pragma unroll
  for (int r = 0; r < 4; ++r) rs[r] = rscale[rb + kg * 4 + r];
#pragma unroll
  for (int ct = 0; ct < 8; ++ct) {
    float s = 0.f;
#pragma unroll
    for (int r = 0; r < 4; ++r) s += expf(acc[ct][r] * rs[r]);
    atomicAdd(&cred2[ct * 16 + m16], s);
  }
  __syncthreads();
  if (tid < 128) atomicAdd(&SBT[tid], cred2[tid]);
}

__global__ __launch_bounds__(256) void k_featall(
    const u16* __restrict__ c_state, const float* __restrict__ rs_state, u16* __restrict__ AxS,
    const u16* __restrict__ c_next, const float* __restrict__ rs_next, u16* __restrict__ ByN,
    float* __restrict__ SBN,
    const u16* __restrict__ ft, const float* __restrict__ rs_ft, u16* __restrict__ AxP,
    const int* __restrict__ text, const u16* __restrict__ c_term,
    const float* __restrict__ rs_term, u16* __restrict__ Btok,
    float* __restrict__ SBT, const u16* __restrict__ PT) {
  const int b = blockIdx.x;
  if (b < 64) feat_body(c_state, rs_state, PT, AxS, b, nullptr);
  else if (b < 128) feat_body(c_next, rs_next, PT, ByN, b - 64, SBN);
  else if (b < 192) feat_body(ft, rs_ft, PT, AxP, b - 128, nullptr);
  else if (b < 256) gather_body(text, c_term, rs_term, PT, Btok, b - 192);
  else colsum_body(c_term, rs_term, PT, SBT, b - 256);
}

// ---------------- per-state scalars ----------------
__global__ __launch_bounds__(256) void k_vecdots(
    const u16* __restrict__ AxS, const u16* __restrict__ AxP, const u16* __restrict__ ByN,
    const float* __restrict__ SBN, const float* __restrict__ SBT, const float* __restrict__ ex0,
    float* __restrict__ recip_r, float* __restrict__ recip_den,
    float* __restrict__ start_raw) {
  const int w = threadIdx.x >> 6, lane = threadIdx.x & 63;
  const int c = blockIdx.x * 4 + w;
  const int d = lane * 2;
  float a0 = bf2f(AxS[(size_t)c * 128 + d]), a1 = bf2f(AxS[(size_t)c * 128 + d + 1]);
  float t = wred64(a0 * SBN[d] + a1 * SBN[d + 1]);
  float p0 = bf2f(AxP[(size_t)c * 128 + d]), p1 = bf2f(AxP[(size_t)c * 128 + d + 1]);
  float p = wred64(p0 * SBT[d] + p1 * SBT[d + 1]);
  float y0 = bf2f(ByN[(size_t)c * 128 + d]), y1 = bf2f(ByN[(size_t)c * 128 + d + 1]);
  float s = wred64(y0 * ex0[d] + y1 * ex0[d + 1]);
  if (lane == 0) {
    recip_r[c] = 1.0f / t;
    recip_den[c] = 1.0f / p;
    start_raw[c] = s;
  }
}

// ---------------- fold/transpose 3 jobs ----------------
__global__ void k_foldT3(const u16* __restrict__ A0, const float* __restrict__ s0, u16* __restrict__ D0,
                         const u16* __restrict__ A1, const float* __restrict__ s1, u16* __restrict__ D1,
                         const u16* __restrict__ A2, u16* __restrict__ D2) {
  int i = blockIdx.x * 256 + threadIdx.x;
  int job = i >> 19;
  int r = i & 524287;
  int d = r >> 12, c = r & 4095;
  if (job == 0) D0[r] = f2bf(bf2f(A0[c * 128 + d]) * s0[c]);
  else if (job == 1) D1[r] = f2bf(bf2f(A1[c * 128 + d]) * s1[c]);
  else D2[r] = A2[c * 128 + d];
}

// ---------------- GEMM-1, LDS-pipelined; K-split x4 (1024-wide chunks) ----------------
__global__ __launch_bounds__(256) void k_gemm1(const u16* __restrict__ ByNT,
                                               const u16* __restrict__ AxS2T,
                                               const u16* __restrict__ AxP2T,
                                               float* __restrict__ Gp) {
  __shared__ __align__(16) u16 Ps[2][8192];
  const int tid = threadIdx.x, lane = tid & 63, w = tid >> 6;
  const int m16 = lane & 15, kg = lane >> 4;
  const int dp = blockIdx.x;
  const int kc = blockIdx.y;
  const int c0 = kc * 1024;
  const floatx4 z4 = {0.f, 0.f, 0.f, 0.f};
  floatx4 acc[2][8];
#pragma unroll
  for (int ct = 0; ct < 8; ++ct) { acc[0][ct] = z4; acc[1][ct] = z4; }
  bf16x8 Xr[2][4];
  bf16x8 Yr[2][2];

#define STAGE(P, cc) do {                                                     \
    const int cb_ = c0 + (cc) * 64;                                           \
    _Pragma("unroll")                                                         \
    for (int j_ = 0; j_ < 4; ++j_) {                                          \
      const u32 Lb_ = (u32)(j_ * 256 + tid) * 16u;                            \
      const u32 U_ = Lb_ ^ (((Lb_ >> 7) & 7u) << 4);                          \
      gload16(AxP2T + (size_t)(U_ >> 7) * 4096 + cb_ + ((U_ & 127u) >> 1),    \
              (char*)&Ps[P][0] + (j_ * 256 + w * 64) * 16);                   \
    }                                                                         \
  } while (0)

#define REGLOAD(P, cc) do {                                                   \
    const int cb_ = c0 + (cc) * 64 + kg * 8;                                  \
    Xr[P][0] = ld8(ByNT + (size_t)(32 * w + m16) * 4096 + cb_);               \
    Xr[P][1] = ld8(ByNT + (size_t)(32 * w + 16 + m16) * 4096 + cb_);          \
    Xr[P][2] = ld8(ByNT + (size_t)(32 * w + m16) * 4096 + cb_ + 32);          \
    Xr[P][3] = ld8(ByNT + (size_t)(32 * w + 16 + m16) * 4096 + cb_ + 32);     \
    if (dp < 128) {                                                           \
      Yr[P][0] = ld8(AxS2T + (size_t)dp * 4096 + cb_);                        \
      Yr[P][1] = ld8(AxS2T + (size_t)dp * 4096 + cb_ + 32);                   \
    }                                                                         \
  } while (0)

#define CHUNK(P) do {                                                         \
    _Pragma("unroll")                                                         \
    for (int kk_ = 0; kk_ < 2; ++kk_) {                                       \
      bf16x8 a0_, a1_;                                                        \
      if (dp < 128) {                                                         \
        bf16x8 yv_ = Yr[P][kk_];                                              \
        _Pragma("unroll")                                                     \
        for (int i_ = 0; i_ < 8; ++i_) {                                      \
          a0_[i_] = (__bf16)((float)Xr[P][kk_ * 2][i_] * (float)yv_[i_]);     \
          a1_[i_] = (__bf16)((float)Xr[P][kk_ * 2 + 1][i_] * (float)yv_[i_]); \
        }                                                                     \
      } else { a0_ = Xr[P][kk_ * 2]; a1_ = Xr[P][kk_ * 2 + 1]; }              \
      const int kb_ = (kk_ * 32 + kg * 8) * 2;                                \
      _Pragma("unroll")                                                       \
      for (int ct_ = 0; ct_ < 8; ++ct_) {                                     \
        const int e_ = ct_ * 16 + m16;                                        \
        bf16x8 bf_ = *(const bf16x8*)((const char*)&Ps[P][0] +                \
                       (u32)(((e_ << 7) + kb_) ^ ((e_ & 7) << 4)));           \
        acc[0][ct_] = MFMA16(a0_, bf_, acc[0][ct_]);                          \
        acc[1][ct_] = MFMA16(a1_, bf_, acc[1][ct_]);                          \
      }                                                                       \
    }                                                                         \
  } while (0)

  STAGE(0, 0);
  REGLOAD(0, 0);
#pragma unroll
  for (int cc = 0; cc < 16; ++cc) {
    __syncthreads();
    if (cc < 15) { STAGE((cc + 1) & 1, cc + 1); REGLOAD((cc + 1) & 1, cc + 1); }
    CHUNK(cc & 1);
  }

#undef STAGE
#undef REGLOAD
#undef CHUNK

  float* gp = Gp + (size_t)kc * 16512 * 128;
  const int rbase = dp * 128 + 32 * w;
#pragma unroll
  for (int t = 0; t < 2; ++t)
#pragma unroll
    for (int ct = 0; ct < 8; ++ct)
#pragma unroll
      for (int r = 0; r < 4; ++r)
        gp[(size_t)(rbase + t * 16 + kg * 4 + r) * 128 + ct * 16 + m16] = acc[t][ct][r];
}

// ---------------- reduce 4 K-chunk partials -> bf16 G (two layouts) ----------------
__global__ __launch_bounds__(256) void k_gred(const float* __restrict__ Gp,
                                              u16* __restrict__ G, u16* __restrict__ G2) {
  const int i = blockIdx.x * 256 + threadIdx.x;   // grid 8256 -> i < 2113536
  const size_t S = (size_t)16512 * 128;
  float s = 0.f;
#pragma unroll
  for (int k = 0; k < 4; ++k) s += Gp[i + k * S];
  u16 v = f2bf(s);
  G[i] = v;
  const int x = i >> 7, e = i & 127;
  if (x < 16384) {
    const int y = ((x & 127) << 7) | (x >> 7);
    G2[(size_t)y * 128 + e] = v;
  }
}

// ---------------- GEMM-2: linear grid padded to 136 columns (XCD-pinned bx) ----------------
__global__ __launch_bounds__(256) void k_gemm2(const u16* __restrict__ A, const u16* __restrict__ Gm,
                                               const u16* __restrict__ Gm2,
                                               u16* __restrict__ Bo, u16* __restrict__ Be) {
  __shared__ __align__(16) u16 ot[128][136];
  const int b = blockIdx.x;          // 0..4351 (136 x 32)
  const int bx = b % 136;
  if (bx >= 129) return;
  const int by = b / 136;            // 0..31
  const int tid = threadIdx.x, lane = tid & 63, w = tid >> 6;
  const int m16 = lane & 15, kg = lane >> 4;
  const int pass = by >> 4;          // 0 = odd-t, 1 = even-t
  if (pass == 1 && bx == 128) return;
  const int mb = (by & 15) * 128 + w * 32;   // q-space row base
  const int nb = bx * 128;
  const int off = pass ? 0 : 16;
  const int nt0 = 2 * mb + off + m16;
  const int nt1 = 2 * mb + 32 + off + m16;
  const u16* Gs = pass ? Gm2 : Gm;
  const floatx4 z4 = {0.f, 0.f, 0.f, 0.f};
  floatx4 acc[2][8];
#pragma unroll
  for (int rt = 0; rt < 2; ++rt)
#pragma unroll
    for (int ct = 0; ct < 8; ++ct) acc[rt][ct] = z4;
  for (int k0 = 0; k0 < 128; k0 += 32) {
    bf16x8 a0 = ld8(A + (size_t)nt0 * 128 + k0 + kg * 8);
    bf16x8 a1 = ld8(A + (size_t)nt1 * 128 + k0 + kg * 8);
#pragma unroll
    for (int ct = 0; ct < 8; ++ct) {
      bf16x8 bb = ld8(Gs + (size_t)(nb + ct * 16 + m16) * 128 + k0 + kg * 8);
      acc[0][ct] = MFMA16(a0, bb, acc[0][ct]);
      acc[1][ct] = MFMA16(a1, bb, acc[1][ct]);
    }
  }
  // stage tile in LDS
#pragma unroll
  for (int rt = 0; rt < 2; ++rt)
#pragma unroll
    for (int ct = 0; ct < 8; ++ct)
#pragma unroll
      for (int r = 0; r < 4; ++r)
        ot[w * 32 + rt * 16 + kg * 4 + r][ct * 16 + m16] = f2bf(acc[rt][ct][r]);
  __syncthreads();
  // full-line stores: 2048 uint4 chunks, 16 per row (256B contiguous)
  const int qbase = (by & 15) * 128;
  u16* Bp = pass ? Be : Bo;
  const size_t stride = pass ? 16384 : 16512;
#pragma unroll
  for (int c = tid; c < 2048; c += 256) {
    const int row = c >> 4, cc = (c & 15) * 8;
    *(uint4*)(Bp + (size_t)(qbase + row) * stride + nb + cc) =
        *(const uint4*)(&ot[row][cc]);
  }
}

// ---------------- fused quad compose (replaces pairA + quadB):
// one block per q2. Phases:
//  A: stage Bo0 -> Sa (144 rows), Be0 -> Sb (128 rows)     [68KB]
//  B: P01 = Be0 x Bo0 (x4096) -> Pl (LDS only, never global)
//  C: restage Bo1 -> Sa, Be1 -> Sb
//  D: per 16-row strip s: P23 strip = Bo1 x Be1 (x4096) -> St;
//     D2 strip = St @ Pl -> regs -> St (linear) -> 256B-chunk global writes.
// LBYTE takes the BYTE column within a 256-byte row (round-14 convention):
// byteaddr = row*256 + colb, XOR-swizzled by (row&7)<<4.
__global__ __launch_bounds__(256) void k_quadF(const u16* __restrict__ Bo,
                                               const u16* __restrict__ Be,
                                               u16* __restrict__ D2) {
  __shared__ __align__(16) u16 Sa[144 * 128];
  __shared__ __align__(16) u16 Sb[128 * 128];
  __shared__ __align__(16) u16 Pl[128 * 128];
  __shared__ __align__(16) u16 St[16 * 128];
  const int tid = threadIdx.x, lane = tid & 63, w = tid >> 6;
  const int m16 = lane & 15, kg = lane >> 4;
  const int q2 = blockIdx.x;
  const int q1a = 2 * (q2 & ~15) + (q2 & 15);
  const int q1b = q1a + 16;
  const floatx4 z4 = {0.f, 0.f, 0.f, 0.f};
  u16* dst = D2 + (size_t)q2 * 16512;

#define LBYTE(row, colb) ((u32)((row) * 256 + (colb)) ^ (u32)(((row) & 7) << 4))

#define STAGE_AB(Asrc, Bsrc) do {                                             \
    _Pragma("unroll")                                                         \
    for (int it = 0; it < 9; ++it) {                                          \
      const u32 c = (u32)(it * 256 + tid);                                    \
      const u32 g = c ^ ((c >> 4) & 7u);                                      \
      gload16((const char*)(Asrc) + g * 16, (char*)Sa + (it * 256 + w * 64) * 16); \
    }                                                                         \
    _Pragma("unroll")                                                         \
    for (int it = 0; it < 8; ++it) {                                          \
      const u32 c = (u32)(it * 256 + tid);                                    \
      const u32 g = c ^ ((c >> 4) & 7u);                                      \
      gload16((const char*)(Bsrc) + g * 16, (char*)Sb + (it * 256 + w * 64) * 16); \
    }                                                                         \
    asm volatile("s_waitcnt vmcnt(0)" ::: "memory");                          \
    __syncthreads();                                                          \
  } while (0)

  // Phase A: Sa <- Bo0 (129+ rows), Sb <- Be0 (128 rows)
  STAGE_AB(Bo + (size_t)q1a * 16512, Be + (size_t)q1a * 16384);

  // Phase B: Pl = Be0 x Bo0 (rows from Sb, cols from Sa), x4096
  for (int ti = w; ti < 64; ti += 4) {
    const int mi = ti >> 3, ni = ti & 7;
    floatx4 acc = z4;
#pragma unroll
    for (int kk = 0; kk < 4; ++kk) {
      const int ar = mi * 16 + m16, br = ni * 16 + m16;
      acc = MFMA16(*(const bf16x8*)((const char*)Sb + LBYTE(ar, (kk * 32 + kg * 8) * 2)),
                   *(const bf16x8*)((const char*)Sa + LBYTE(br, (kk * 32 + kg * 8) * 2)),
                   acc);
    }
#pragma unroll
    for (int r = 0; r < 4; ++r) {
      const int row = mi * 16 + kg * 4 + r, col = ni * 16 + m16;
      *(u16*)((char*)Pl + LBYTE(row, col * 2)) = f2bf(acc[r] * 4096.0f);
    }
  }
  __syncthreads();

  // Phase C: restage Sa <- Bo1, Sb <- Be1
  STAGE_AB(Bo + (size_t)q1b * 16512, Be + (size_t)q1b * 16384);

  // Phase D: 9 strips of 16 rows
  for (int s = 0; s < 9; ++s) {
    // P23 strip (rows 16s..16s+15) = Bo1 x Be1, x4096 -> St (LBYTE layout)
#pragma unroll
    for (int j = 0; j < 2; ++j) {
      const int ni = w * 2 + j;
      floatx4 acc = z4;
#pragma unroll
      for (int kk = 0; kk < 4; ++kk) {
        const int ar = s * 16 + m16, br = ni * 16 + m16;
        acc = MFMA16(*(const bf16x8*)((const char*)Sa + LBYTE(ar, (kk * 32 + kg * 8) * 2)),
                     *(const bf16x8*)((const char*)Sb + LBYTE(br, (kk * 32 + kg * 8) * 2)),
                     acc);
      }
#pragma unroll
      for (int r = 0; r < 4; ++r) {
        const int rl = kg * 4 + r, col = ni * 16 + m16;
        *(u16*)((char*)St + LBYTE(rl, col * 2)) = f2bf(acc[r] * 4096.0f);
      }
    }
    __syncthreads();
    // D2 strip = St @ Pl -> regs
    floatx4 o[2];
#pragma unroll
    for (int j = 0; j < 2; ++j) {
      const int ni = w * 2 + j;
      floatx4 acc = z4;
#pragma unroll
      for (int kk = 0; kk < 4; ++kk) {
        acc = MFMA16(*(const bf16x8*)((const char*)St + LBYTE(m16, (kk * 32 + kg * 8) * 2)),
                     *(const bf16x8*)((const char*)Pl + LBYTE(ni * 16 + m16, (kk * 32 + kg * 8) * 2)),
                     acc);
      }
      o[j] = acc;
    }
    __syncthreads();   // St consumers done
    // route through St (linear layout) for 256B-chunk global writes
#pragma unroll
    for (int j = 0; j < 2; ++j) {
      const int ni = w * 2 + j;
#pragma unroll
      for (int r = 0; r < 4; ++r)
        *(u16*)((char*)St + (u32)((kg * 4 + r) * 256 + (ni * 16 + m16) * 2)) = f2bf(o[j][r]);
    }
    __syncthreads();
    {
      const int row = tid >> 4, cc = (tid & 15) * 8;
      const int dF = s * 16 + row;
      if (dF < 129)
        *(uint4*)(dst + (size_t)dF * 128 + cc) = *(const uint4*)((char*)St + row * 256 + cc * 2);
    }
    __syncthreads();
  }
#undef STAGE_AB
#undef LBYTE
}

// ---------------- scan: 16 blocks, 64 steps over composed quads (R4 structure).
__global__ __launch_bounds__(256) void k_scan2(const u16* __restrict__ Bm,
                                               const float* __restrict__ ex0,
                                               float* __restrict__ evp) {
  __shared__ __align__(16) u16 vb[2][128];
  const int tid = threadIdx.x, lane = tid & 63, w = tid >> 6;
  const int m16 = lane & 15, kg = lane >> 4;
  const int n = blockIdx.x;
  const int g0 = w * 2, g1 = w * 2 + 1;
  const int offA0 = (g0 * 16 + m16) * 128 + kg * 8;
  const int offA1 = (g1 * 16 + m16) * 128 + kg * 8;
  const int offS = 16384 + lane * 2;
  const floatx4 z4 = {0.f, 0.f, 0.f, 0.f};

  if (tid < 128) vb[0][tid] = f2bf(ex0[tid]);
  int esum = 0;
  float finlog = 0.f;

  bf16x8 A0[2][4], A1[2][4], A2[2][4];
  u32 s0 = 0, s1 = 0, s2 = 0;

#define PREF(t, A, S) do {                                                   \
    const u16* rp_ = Bm + (size_t)((((t) << 4) | n)) * 16512;                \
    A[0][0] = ld8(rp_ + offA0);      A[0][1] = ld8(rp_ + offA0 + 32);        \
    A[0][2] = ld8(rp_ + offA0 + 64); A[0][3] = ld8(rp_ + offA0 + 96);        \
    A[1][0] = ld8(rp_ + offA1);      A[1][1] = ld8(rp_ + offA1 + 32);        \
    A[1][2] = ld8(rp_ + offA1 + 64); A[1][3] = ld8(rp_ + offA1 + 96);        \
    S = *(const u32*)(rp_ + offS);                                           \
  } while (0)

#define STEP(t, A, S) do {                                                   \
    if ((t) < 62)       asm volatile("s_waitcnt vmcnt(18)" ::: "memory");    \
    else if ((t) == 62) asm volatile("s_waitcnt vmcnt(9)" ::: "memory");     \
    else                asm volatile("s_waitcnt vmcnt(0)" ::: "memory");     \
    asm volatile("s_waitcnt lgkmcnt(0)" ::: "memory");                       \
    __builtin_amdgcn_s_barrier();                                            \
    const u16* vc_ = vb[(t) & 1];                                            \
    u32 vpair_ = *(const u32*)(vc_ + lane * 2);                              \
    float sdot_ = bf2f((u16)(vpair_ & 0xFFFFu)) * bf2f((u16)((S) & 0xFFFFu)) \
                + bf2f((u16)(vpair_ >> 16)) * bf2f((u16)((S) >> 16));        \
    _Pragma("unroll")                                                        \
    for (int of_ = 1; of_ < 64; of_ <<= 1) sdot_ += __shfl_xor(sdot_, of_, 64); \
    if ((t) == 63) {                                                         \
      finlog = logf(sdot_);                                                  \
    } else {                                                                 \
      bf16x8 b0_ = *(const bf16x8*)(vc_ + kg * 8);                           \
      bf16x8 b1_ = *(const bf16x8*)(vc_ + 32 + kg * 8);                      \
      bf16x8 b2_ = *(const bf16x8*)(vc_ + 64 + kg * 8);                      \
      bf16x8 b3_ = *(const bf16x8*)(vc_ + 96 + kg * 8);                      \
      floatx4 ac0_ = z4, ac1_ = z4;                                          \
      ac0_ = MFMA16(A[0][0], b0_, ac0_); ac1_ = MFMA16(A[1][0], b0_, ac1_);  \
      ac0_ = MFMA16(A[0][1], b1_, ac0_); ac1_ = MFMA16(A[1][1], b1_, ac1_);  \
      ac0_ = MFMA16(A[0][2], b2_, ac0_); ac1_ = MFMA16(A[1][2], b2_, ac1_);  \
      ac0_ = MFMA16(A[0][3], b3_, ac0_); ac1_ = MFMA16(A[1][3], b3_, ac1_);  \
      u32 sb_; __builtin_memcpy(&sb_, &sdot_, 4);                            \
      int e_ = (int)((sb_ >> 23) & 255u) - 127;                              \
      esum += e_;                                                            \
      float scale_; { u32 se_ = (u32)(127 - e_) << 23;                       \
                      __builtin_memcpy(&scale_, &se_, 4); }                  \
      if (m16 == 0) {                                                        \
        u16 p0_[4], p1_[4];                                                  \
        _Pragma("unroll")                                                    \
        for (int r_ = 0; r_ < 4; ++r_) {                                     \
          p0_[r_] = f2bf(ac0_[r_] * scale_);                                 \
          p1_[r_] = f2bf(ac1_[r_] * scale_);                                 \
        }                                                                    \
        u16* dst_ = vb[((t) + 1) & 1];                                       \
        uint2 q0_, q1_;                                                      \
        __builtin_memcpy(&q0_, p0_, 8); __builtin_memcpy(&q1_, p1_, 8);      \
        *(uint2*)(dst_ + g0 * 16 + kg * 4) = q0_;                            \
        *(uint2*)(dst_ + g1 * 16 + kg * 4) = q1_;                            \
      }                                                                      \
    }                                                                        \
    if ((t) + 3 < 64) PREF((t) + 3, A, S);                                   \
  } while (0)

  PREF(0, A0, s0);
  PREF(1, A1, s1);
  PREF(2, A2, s2);

  for (int tt = 0; tt < 63; tt += 3) {
    STEP(tt, A0, s0);
    STEP(tt + 1, A1, s1);
    STEP(tt + 2, A2, s2);
  }
  STEP(63, A0, s0);

#undef PREF
#undef STEP

  if (tid == 0) evp[n] = finlog + 0.6931471805599453f * (float)(esum - 1536);
}

// ---------------- final ----------------
__global__ void k_final(const float* __restrict__ evp, const float* __restrict__ SBN,
                        const float* __restrict__ ex0, const int* __restrict__ flag,
                        u16* __restrict__ outp) {
  if (threadIdx.x == 0 && blockIdx.x == 0) {
    float ev = 0.f;
    for (int i = 0; i < 16; ++i) ev += evp[i];
    float ssum = 0.f;
    for (int d = 0; d < 128; ++d) ssum += SBN[d] * ex0[d];
    ev -= 16.0f * logf(ssum);
    store_final(outp, ev, *flag);
  }
}

extern "C" void kernel_launch(void* const* d_in, const int* in_sizes, int n_in,
                              void* d_out, int out_size, void* d_ws, size_t ws_size,
                              hipStream_t stream) {
  (void)out_size;
  u16* outp = (u16*)d_out;
  if (n_in != 26 || in_sizes[25] != 128 * 256) {
    k_sentinel<<<1, 1, 0, stream>>>(outp, 5000.0f + (float)n_in);
    return;
  }
  const int* text = (const int*)d_in[0];

  char* base = (char*)d_ws;
  size_t off = 0;
  auto take = [&](size_t bytes) -> char* {
    char* p = base + off;
    off = (off + bytes + 255) & ~(size_t)255;
    return p;
  };
  int* flag = (int*)take(256);
  u16* c_se   = (u16*)take(256 * 2);
  u16* c_w[18];
  for (int i = 0; i < 18; ++i) c_w[i] = (u16*)take(((i & 1) ? 256 : 65536) * 2);
  u16* c_state = (u16*)take((size_t)1048576 * 2);
  u16* c_next  = (u16*)take((size_t)1048576 * 2);
  u16* c_pre   = (u16*)take((size_t)1048576 * 2);
  u16* c_term  = (u16*)take((size_t)8192000 * 2);
  u16* c_proj  = (u16*)take((size_t)32768 * 2);
  u16* projT  = (u16*)take(128 * 256 * 2);
  u16* twT1   = (u16*)take(65536 * 2);
  u16* twT2   = (u16*)take(65536 * 2);
  u16* twT3   = (u16*)take(65536 * 2);
  u16* twT4   = (u16*)take(65536 * 2);
  u16* ft     = (u16*)take((size_t)4096 * 256 * 2);
  float* rs_state = (float*)take(4096 * 4);
  float* rs_next  = (float*)take(4096 * 4);
  float* rs_ft    = (float*)take(4096 * 4);
  float* rs_term  = (float*)take(32000 * 4);
  u16* AxS    = (u16*)take((size_t)4096 * 128 * 2);
  u16* ByN    = (u16*)take((size_t)4096 * 128 * 2);
  u16* AxP    = (u16*)take((size_t)4096 * 128 * 2);
  u16* Btok   = (u16*)take((size_t)4096 * 128 * 2);
  u16* AxS2T  = (u16*)take((size_t)128 * 4096 * 2);
  u16* AxP2T  = (u16*)take((size_t)128 * 4096 * 2);
  u16* ByNT   = (u16*)take((size_t)128 * 4096 * 2);
  u16* Gm     = (u16*)take((size_t)16512 * 128 * 2);
  u16* Gm2    = (u16*)take((size_t)16384 * 128 * 2);
  u16* Bo     = (u16*)take((size_t)2049 * 16512 * 2);   // odd-t matrices, out-major
  u16* Be     = (u16*)take((size_t)2049 * 16384 * 2);   // even-t matrices, in-major
  u16* D2buf  = (u16*)take((size_t)1025 * 16512 * 2);   // composed quads, out-major
  float* recip_r   = (float*)take(4096 * 4);
  float* recip_den = (float*)take(4096 * 4);
  float* start_raw = (float*)take(4096 * 4);
  float* ex0       = (float*)take(132 * 4);
  float* zreg = (float*)take(2048);   // SBN | SBT (zeroed)
  float* SBN = zreg, *SBT = zreg + 128;
  float* evp = (float*)take(64);
  // Gpart (4 x 16512 x 128 f32 = 33.8 MB) aliases Bo (67.7 MB): gemm1 writes
  // it, gred consumes it, then gemm2 overwrites Bo. Stream-ordered -> safe.
  float* Gpart = (float*)Bo;

  const float ws_mb = (float)(ws_size >> 20) > 900.f ? 900.f : (float)(ws_size >> 20);
  if (off > ws_size) {
    k_sentinel<<<1, 1, 0, stream>>>(outp, 1000.0f + ws_mb);
    return;
  }

  k_detect<<<1, 64, 0, stream>>>((const u32*)d_in[25], flag);
  k_sentinel<<<1, 1, 0, stream>>>(outp, -7777.0f);  // breadcrumb
  hipMemsetAsync(zreg, 0, 2048, stream);

  // fused convert: 24 jobs
  CvtJobs cj;
  int cb_ = 0, cjn = 0;
  auto addcvt = [&](const void* s, u16* d, int n) {
    cj.src[cjn] = s; cj.dst[cjn] = d; cj.n[cjn] = n;
    cj.bstart[cjn] = cb_; cb_ += (n + 4095) / 4096; ++cjn;
  };
  addcvt(d_in[2], c_se, 256);
  for (int i = 0; i < 18; ++i) addcvt(d_in[3 + i], c_w[i], (i & 1) ? 256 : 65536);
  addcvt(d_in[21], c_state, 1048576);
  addcvt(d_in[22], c_next, 1048576);
  addcvt(d_in[23], c_pre, 1048576);
  addcvt(d_in[24], c_term, 8192000);
  addcvt(d_in[25], c_proj, 32768);
  cj.bstart[24] = cb_;
  k_cvt_all<<<cb_, 256, 0, stream>>>(cj, flag);

  // fused transposes: 5 jobs
  TrJobs tj;
  tj.src[0] = c_proj; tj.dst[0] = projT; tj.R[0] = 256; tj.C[0] = 128;
  tj.src[1] = c_w[10]; tj.dst[1] = twT1; tj.R[1] = 256; tj.C[1] = 256;
  tj.src[2] = c_w[12]; tj.dst[2] = twT2; tj.R[2] = 256; tj.C[2] = 256;
  tj.src[3] = c_w[14]; tj.dst[3] = twT3; tj.R[3] = 256; tj.C[3] = 256;
  tj.src[4] = c_w[16]; tj.dst[4] = twT4; tj.R[4] = 256; tj.C[4] = 256;
  int tb = 0;
  for (int j = 0; j < 5; ++j) { tj.bstart[j] = tb; tb += (tj.R[j] * tj.C[j]) / 1024; }
  tj.bstart[5] = tb;
  k_transpose_all<<<tb, 256, 0, stream>>>(tj);

  // fused rownorm: state, next, term
  RnJobs rj;
  rj.X[0] = c_state; rj.out[0] = rs_state; rj.rows[0] = 4096;
  rj.X[1] = c_next;  rj.out[1] = rs_next;  rj.rows[1] = 4096;
  rj.X[2] = c_term;  rj.out[2] = rs_term;  rj.rows[2] = 32000;
  rj.bstart[0] = 0; rj.bstart[1] = 1024; rj.bstart[2] = 2048; rj.bstart[3] = 10048;
  k_rownorm_all<<<10048, 256, 0, stream>>>(rj);

  k_start<<<1, 256, 0, stream>>>(c_se, c_w[0], c_w[1], c_w[2], c_w[3], c_w[4], c_w[5],
                                 c_w[6], c_w[7], c_w[8], c_w[9], c_proj, ex0);
  k_mlp<<<64, 256, 0, stream>>>(c_pre, twT1, c_w[11], twT2, c_w[13], twT3, c_w[15],
                                twT4, c_w[17], ft, rs_ft);
  k_featall<<<756, 256, 0, stream>>>(c_state, rs_state, AxS, c_next, rs_next, ByN, SBN,
                                     ft, rs_ft, AxP, text, c_term, rs_term, Btok,
                                     SBT, projT);
  k_vecdots<<<1024, 256, 0, stream>>>(AxS, AxP, ByN, SBN, SBT, ex0, recip_r, recip_den,
                                      start_raw);
  k_foldT3<<<6144, 256, 0, stream>>>(AxS, recip_r, AxS2T, AxP, recip_den, AxP2T, ByN, ByNT);
  k_gemm1<<<dim3(129, 4), 256, 0, stream>>>(ByNT, AxS2T, AxP2T, Gpart);
  k_gred<<<8256, 256, 0, stream>>>(Gpart, Gm, Gm2);
  k_gemm2<<<4352, 256, 0, stream>>>(Btok, Gm, Gm2, Bo, Be);
  k_quadF<<<1024, 256, 0, stream>>>(Bo, Be, D2buf);
  k_scan2<<<16, 256, 0, stream>>>(D2buf, ex0, evp);
  k_final<<<1, 64, 0, stream>>>(evp, SBN, ex0, flag, outp);
}